// Round 7
// baseline (436.248 us; speedup 1.0000x reference)
//
#include <hip/hip_runtime.h>
#include <hip/hip_bf16.h>

// ---------------------------------------------------------------------------
// GraphTransformerBlock: TransformerConv(H=2, C=128) + skip + LN + FFN + LN
// R7: fused_attn = 1 wave/node, 4-edge static ping-pong (8 KV gathers in
// flight), fused head-mean epilogue. CSR: memset + deg_count folded into
// prep, scan_finalize/rowp deleted (row bounds from tmp+scanned bsum).
// x->bf16 cast folded into proj GEMM staging. 10 dispatches.
// O1 row [1024]: q 0-255 | kv-interleaved 256-767 | skip 768-895 | P 896-959
// ---------------------------------------------------------------------------

typedef __attribute__((ext_vector_type(8))) short bf16x8;
typedef __attribute__((ext_vector_type(8))) unsigned short u16x8;
typedef __attribute__((ext_vector_type(4))) float f32x4;

__device__ __forceinline__ float bf2f(unsigned short u) {
    union { float f; unsigned u32; } x; x.u32 = ((unsigned)u) << 16; return x.f;
}
__device__ __forceinline__ unsigned short f2bf(float f) {
    unsigned u = __float_as_uint(f);
    return (unsigned short)((u + 0x7FFFu + ((u >> 16) & 1u)) >> 16);
}

// ---------------- bf16 MFMA GEMM + optional fused LN epilogue ---------------
// C[M,OC] = act(A[M,K] @ W[OC,K]^T + bias)
// AF32=1: A is fp32, converted to bf16 during LDS staging.
// EPI=0: plain store. EPI=1 (grid.x==1, OC=128): t = acc+add0+add1+bf16(skip);
// out = LN(t) -> bf16. EPI=2: f = acc+bias; t = bf16(hprev)+f; LN -> f32.
template<int ACT, int EPI, int OUT_BF16, int AF32>
__global__ __launch_bounds__(256)
void gemm_fused(const void* __restrict__ Ap, int lda,
                const unsigned short* __restrict__ W, int ldw,
                const float* __restrict__ bias,
                void* __restrict__ outp, int ldo, int M, int K,
                const float* __restrict__ add0, const float* __restrict__ add1,
                const unsigned short* __restrict__ skipp, int skip_ld,
                const unsigned short* __restrict__ hprev,
                const float* __restrict__ lng, const float* __restrict__ lnb) {
    __shared__ unsigned short As[128 * 40];   // pitch 40 elems kills conflicts
    __shared__ unsigned short Bs[128 * 40];
    const int tid = threadIdx.x;
    const int wave = tid >> 6, lane = tid & 63;
    const int row0 = blockIdx.y * 128, col0 = blockIdx.x * 128;
    const int srow = tid >> 2;
    const int skg  = (tid & 3) * 8;
    int r0 = row0 + srow;      if (r0 >= M) r0 = 0;
    int r1 = row0 + srow + 64; if (r1 >= M) r1 = 0;
    const int b0 = col0 + srow, b1 = col0 + srow + 64;

    f32x4 acc[2][8];
    const f32x4 z4 = {0.f, 0.f, 0.f, 0.f};
    #pragma unroll
    for (int i = 0; i < 2; i++)
        #pragma unroll
        for (int j = 0; j < 8; j++) acc[i][j] = z4;

    const int mrow = wave * 32 + (lane & 15);
    const int kq = (lane >> 4) * 8;

    for (int kt = 0; kt < K; kt += 32) {
        u16x8 a0v, a1v;
        if (AF32) {
            const float* Af = (const float*)Ap;
            float4 xa = *(const float4*)(Af + (size_t)r0 * lda + kt + skg);
            float4 xb = *(const float4*)(Af + (size_t)r0 * lda + kt + skg + 4);
            float4 ya = *(const float4*)(Af + (size_t)r1 * lda + kt + skg);
            float4 yb = *(const float4*)(Af + (size_t)r1 * lda + kt + skg + 4);
            a0v[0]=f2bf(xa.x); a0v[1]=f2bf(xa.y); a0v[2]=f2bf(xa.z); a0v[3]=f2bf(xa.w);
            a0v[4]=f2bf(xb.x); a0v[5]=f2bf(xb.y); a0v[6]=f2bf(xb.z); a0v[7]=f2bf(xb.w);
            a1v[0]=f2bf(ya.x); a1v[1]=f2bf(ya.y); a1v[2]=f2bf(ya.z); a1v[3]=f2bf(ya.w);
            a1v[4]=f2bf(yb.x); a1v[5]=f2bf(yb.y); a1v[6]=f2bf(yb.z); a1v[7]=f2bf(yb.w);
        } else {
            const unsigned short* Ah = (const unsigned short*)Ap;
            a0v = *(const u16x8*)(Ah + (size_t)r0 * lda + kt + skg);
            a1v = *(const u16x8*)(Ah + (size_t)r1 * lda + kt + skg);
        }
        float4 w0 = *(const float4*)(W + (size_t)b0 * ldw + kt + skg);
        float4 w1 = *(const float4*)(W + (size_t)b1 * ldw + kt + skg);
        __syncthreads();
        *(u16x8*)&As[srow * 40 + skg]        = a0v;
        *(u16x8*)&As[(srow + 64) * 40 + skg] = a1v;
        *(float4*)&Bs[srow * 40 + skg]        = w0;
        *(float4*)&Bs[(srow + 64) * 40 + skg] = w1;
        __syncthreads();
        bf16x8 af0 = *(const bf16x8*)&As[mrow * 40 + kq];
        bf16x8 af1 = *(const bf16x8*)&As[(mrow + 16) * 40 + kq];
        bf16x8 bfr[8];
        #pragma unroll
        for (int j = 0; j < 8; j++)
            bfr[j] = *(const bf16x8*)&Bs[(j * 16 + (lane & 15)) * 40 + kq];
        #pragma unroll
        for (int j = 0; j < 8; j++) {
            acc[0][j] = __builtin_amdgcn_mfma_f32_16x16x32_bf16(af0, bfr[j], acc[0][j], 0, 0, 0);
            acc[1][j] = __builtin_amdgcn_mfma_f32_16x16x32_bf16(af1, bfr[j], acc[1][j], 0, 0, 0);
        }
    }

    // C/D layout: col = lane&15, row = (lane>>4)*4 + reg
    const int lgrp = lane & 15;
    if (EPI == 0) {
        const int orow0 = row0 + wave * 32 + ((lane >> 4) << 2);
        const int ocol0 = col0 + lgrp;
        #pragma unroll
        for (int i = 0; i < 2; i++) {
            #pragma unroll
            for (int r = 0; r < 4; r++) {
                int row = orow0 + i * 16 + r;
                if (row >= M) continue;
                #pragma unroll
                for (int j = 0; j < 8; j++) {
                    int col = ocol0 + j * 16;
                    float v = acc[i][j][r] + (bias ? bias[col] : 0.f);
                    if (ACT == 1) v = (v > 0.f) ? v : 0.01f * v;
                    if (OUT_BF16) ((unsigned short*)outp)[(size_t)row * ldo + col] = f2bf(v);
                    else          ((float*)outp)[(size_t)row * ldo + col] = v;
                }
            }
        }
    } else {
        #pragma unroll
        for (int i = 0; i < 2; i++) {
            #pragma unroll
            for (int r = 0; r < 4; r++) {
                int row = row0 + wave * 32 + ((lane >> 4) << 2) + i * 16 + r;
                if (row >= M) continue;
                float t[8];
                #pragma unroll
                for (int j = 0; j < 8; j++) {
                    int col = lgrp + j * 16;
                    float v = acc[i][j][r];
                    if (EPI == 1) {
                        v += add0[(size_t)row * 128 + col] + add1[(size_t)row * 128 + col]
                           + bf2f(skipp[(size_t)row * skip_ld + col]);
                    } else {
                        v += bias[col];
                        v += bf2f(hprev[(size_t)row * 128 + col]);
                    }
                    t[j] = v;
                }
                float s = 0.f;
                #pragma unroll
                for (int j = 0; j < 8; j++) s += t[j];
                #pragma unroll
                for (int off = 8; off >= 1; off >>= 1) s += __shfl_xor(s, off);
                float mu = s * (1.f / 128.f);
                float q = 0.f;
                #pragma unroll
                for (int j = 0; j < 8; j++) { float d = t[j] - mu; q += d * d; }
                #pragma unroll
                for (int off = 8; off >= 1; off >>= 1) q += __shfl_xor(q, off);
                float rs = rsqrtf(q * (1.f / 128.f) + 1e-5f);
                #pragma unroll
                for (int j = 0; j < 8; j++) {
                    int col = lgrp + j * 16;
                    float o = (t[j] - mu) * rs * lng[col] + lnb[col];
                    if (EPI == 1) ((unsigned short*)outp)[(size_t)row * ldo + col] = f2bf(o);
                    else          ((float*)outp)[(size_t)row * ldo + col] = o;
                }
            }
        }
    }
}

// ---------------- prep: weights + deg_count, one dispatch -------------------
#define WPREP 205824
__global__ void prep_all(const float* __restrict__ Wq, const float* __restrict__ bq,
                         const float* __restrict__ Wk, const float* __restrict__ bk,
                         const float* __restrict__ Wv, const float* __restrict__ bv,
                         const float* __restrict__ We, const float* __restrict__ Wsk,
                         const float* __restrict__ bsk,
                         const float* __restrict__ W1, const float* __restrict__ W2,
                         unsigned short* __restrict__ Wcat, float* __restrict__ bcat,
                         unsigned short* __restrict__ W1h, unsigned short* __restrict__ W2h,
                         unsigned short* __restrict__ Wec2,
                         const int* __restrict__ dst, int* __restrict__ deg, int E) {
    int k = blockIdx.x * 256 + threadIdx.x;
    if (k >= WPREP) {                       // deg count segment
        int e = k - WPREP;
        if (e < E) atomicAdd(&deg[dst[e]], 1);
        return;
    }
    if (k < 131072) {                       // Wcat [1024][128]
        int oc = k >> 7, r = k & 127;
        float v;
        if (oc < 256) v = Wq[(size_t)oc * 128 + r];
        else if (oc < 768) {
            int rr = oc - 256, g = rr >> 3, p = rr & 7;
            int h = g >> 5, ch = h * 128 + (g & 31) * 4 + (p & 3);
            v = (p < 4) ? Wk[(size_t)ch * 128 + r] : Wv[(size_t)ch * 128 + r];
        } else if (oc < 896) v = Wsk[(size_t)(oc - 768) * 128 + r];
        else if (oc < 960) {
            int qd = oc - 896, h = qd >> 5, t = qd & 31;
            float s = 0.f;
            for (int c = 0; c < 128; c++)
                s += Wq[(size_t)(h*128 + c) * 128 + r] * We[(size_t)(h*128 + c) * 32 + t];
            v = s;
        } else v = 0.f;
        Wcat[k] = f2bf(v);
    } else if (k < 132096) {                // bcat [1024]
        int oc = k - 131072;
        float v;
        if (oc < 256) v = bq[oc];
        else if (oc < 768) {
            int rr = oc - 256, g = rr >> 3, p = rr & 7;
            int ch = (g >> 5) * 128 + (g & 31) * 4 + (p & 3);
            v = (p < 4) ? bk[ch] : bv[ch];
        } else if (oc < 896) v = bsk[oc - 768];
        else if (oc < 960) {
            int qd = oc - 896, h = qd >> 5, t = qd & 31;
            float s = 0.f;
            for (int c = 0; c < 128; c++)
                s += bq[h*128 + c] * We[(size_t)(h*128 + c) * 32 + t];
            v = s;
        } else v = 0.f;
        bcat[oc] = v;
    } else if (k < 164864) {                // W1h
        int j = k - 132096;
        W1h[j] = f2bf(W1[j]);
    } else if (k < 197632) {                // W2h
        int j = k - 164864;
        W2h[j] = f2bf(W2[j]);
    } else {                                // Wec2 [128][64], 0.5 head-mean folded
        int j = k - 197632;
        int c = j >> 6, tt = j & 63, h = tt >> 5, t = tt & 31;
        Wec2[j] = f2bf(0.5f * We[(size_t)(h * 128 + c) * 32 + t]);
    }
}

// ---------------- CSR scan --------------------------------------------------
__global__ __launch_bounds__(256)
void scan_block(const int* __restrict__ deg, int* __restrict__ tmp,
                int* __restrict__ bsum, int n) {
    __shared__ int lds[256];
    int i = blockIdx.x * 256 + threadIdx.x;
    int v = (i < n) ? deg[i] : 0;
    lds[threadIdx.x] = v;
    __syncthreads();
    #pragma unroll
    for (int off = 1; off < 256; off <<= 1) {
        int t = (threadIdx.x >= off) ? lds[threadIdx.x - off] : 0;
        __syncthreads();
        lds[threadIdx.x] += t;
        __syncthreads();
    }
    if (i < n) tmp[i] = lds[threadIdx.x];
    if (threadIdx.x == 255) bsum[blockIdx.x] = lds[255];
}
__global__ __launch_bounds__(1024)
void scan_bsum(int* __restrict__ bsum, int nb) {
    __shared__ int lds[1024];
    int v = (threadIdx.x < nb) ? bsum[threadIdx.x] : 0;
    lds[threadIdx.x] = v;
    __syncthreads();
    #pragma unroll
    for (int off = 1; off < 1024; off <<= 1) {
        int t = (threadIdx.x >= off) ? lds[threadIdx.x - off] : 0;
        __syncthreads();
        lds[threadIdx.x] += t;
        __syncthreads();
    }
    if (threadIdx.x < nb) bsum[threadIdx.x] = lds[threadIdx.x] - v;  // exclusive
}
// row_start(d) = (d==0) ? 0 : tmp[d-1] + sbx[(d-1)>>8]
__global__ void csr_fill(const int* __restrict__ src, const int* __restrict__ dst,
                         const int* __restrict__ tmp, const int* __restrict__ sbx,
                         int* __restrict__ cnt, int2* __restrict__ eid2, int E) {
    int e = blockIdx.x * blockDim.x + threadIdx.x;
    if (e < E) {
        int d = dst[e];
        int start = (d == 0) ? 0 : (tmp[d - 1] + sbx[(d - 1) >> 8]);
        int pos = start + atomicAdd(&cnt[d], 1);
        eid2[pos] = make_int2(e, src[e]);
    }
}

// ---------------- fused attention: 1 wave/node, 4-edge ping-pong ------------
// 8 KV gathers in flight/wave. Epilogue: per-head normalize, head-mean via
// shfl_xor(32) -> agg[N,128] f32; weab[N,64] bf16.
__global__ __launch_bounds__(256)
void fused_attn(const unsigned short* __restrict__ O1, const float* __restrict__ EA,
                const int* __restrict__ tmp, const int* __restrict__ sbx,
                const int2* __restrict__ eid2,
                float* __restrict__ agg, unsigned short* __restrict__ weab, int N) {
    int node = blockIdx.x * 4 + (threadIdx.x >> 6);
    if (node >= N) return;
    const int lane = threadIdx.x & 63;
    const int hl = lane & 31;
    const int choff = (lane >> 5) * 128 + (hl << 2);
    const float inv = 0.08838834764831845f;  // 1/sqrt(128)

    ushort4 q4 = *(const ushort4*)(O1 + (size_t)node * 1024 + choff);
    float4 qv = make_float4(bf2f(q4.x), bf2f(q4.y), bf2f(q4.z), bf2f(q4.w));
    float pd = bf2f(O1[(size_t)node * 1024 + 896 + lane]);

    const int j0 = (node == 0) ? 0 : (tmp[node - 1] + sbx[(node - 1) >> 8]);
    const int jend = tmp[node] + sbx[node >> 8];

    float l = 0.f, wacc = 0.f;
    float4 acc = make_float4(0.f, 0.f, 0.f, 0.f);

    const u16x8 zkv = {0,0,0,0,0,0,0,0};
    u16x8 kvA0, kvA1, kvA2, kvA3, kvB0, kvB1, kvB2, kvB3;
    float eaA0, eaA1, eaA2, eaA3, eaB0, eaB1, eaB2, eaB3;
    int2 es0, es1, es2, es3;

    #define LD_KV(KV, EAV, ES)                                                  \
        if ((ES).y >= 0) {                                                      \
            KV = *(const u16x8*)(O1 + (size_t)(ES).y * 1024 + 256 + lane * 8);  \
            EAV = EA[(size_t)(ES).x * 32 + hl];                                 \
        } else { KV = zkv; EAV = 0.f; }

    #define COMPUTE(K0, K1, K2, K3, E0, E1, E2, E3)                             \
        {                                                                       \
            float d0 = qv.x*bf2f(K0[0]) + qv.y*bf2f(K0[1])                      \
                     + qv.z*bf2f(K0[2]) + qv.w*bf2f(K0[3]) + pd*E0;             \
            float d1 = qv.x*bf2f(K1[0]) + qv.y*bf2f(K1[1])                      \
                     + qv.z*bf2f(K1[2]) + qv.w*bf2f(K1[3]) + pd*E1;             \
            float d2 = qv.x*bf2f(K2[0]) + qv.y*bf2f(K2[1])                      \
                     + qv.z*bf2f(K2[2]) + qv.w*bf2f(K2[3]) + pd*E2;             \
            float d3 = qv.x*bf2f(K3[0]) + qv.y*bf2f(K3[1])                      \
                     + qv.z*bf2f(K3[2]) + qv.w*bf2f(K3[3]) + pd*E3;             \
            _Pragma("unroll")                                                   \
            for (int off = 16; off >= 1; off >>= 1) {                           \
                d0 += __shfl_xor(d0, off); d1 += __shfl_xor(d1, off);           \
                d2 += __shfl_xor(d2, off); d3 += __shfl_xor(d3, off);           \
            }                                                                   \
            float w0 = (j     < jend) ? __expf(d0 * inv) : 0.f;                 \
            float w1 = (j + 1 < jend) ? __expf(d1 * inv) : 0.f;                 \
            float w2 = (j + 2 < jend) ? __expf(d2 * inv) : 0.f;                 \
            float w3 = (j + 3 < jend) ? __expf(d3 * inv) : 0.f;                 \
            l += (w0 + w1) + (w2 + w3);                                         \
            acc.x += w0*bf2f(K0[4]) + w1*bf2f(K1[4]) + w2*bf2f(K2[4]) + w3*bf2f(K3[4]); \
            acc.y += w0*bf2f(K0[5]) + w1*bf2f(K1[5]) + w2*bf2f(K2[5]) + w3*bf2f(K3[5]); \
            acc.z += w0*bf2f(K0[6]) + w1*bf2f(K1[6]) + w2*bf2f(K2[6]) + w3*bf2f(K3[6]); \
            acc.w += w0*bf2f(K0[7]) + w1*bf2f(K1[7]) + w2*bf2f(K2[7]) + w3*bf2f(K3[7]); \
            wacc  += w0*E0 + w1*E1 + w2*E2 + w3*E3;                             \
        }

    int j = j0;
    if (j < jend) {
        // prologue: indices+kv for chunk 0 -> A, indices chunk 1 -> es
        es0 = (j     < jend) ? eid2[j]     : make_int2(0, -1);
        es1 = (j + 1 < jend) ? eid2[j + 1] : make_int2(0, -1);
        es2 = (j + 2 < jend) ? eid2[j + 2] : make_int2(0, -1);
        es3 = (j + 3 < jend) ? eid2[j + 3] : make_int2(0, -1);
        LD_KV(kvA0, eaA0, es0) LD_KV(kvA1, eaA1, es1)
        LD_KV(kvA2, eaA2, es2) LD_KV(kvA3, eaA3, es3)
        es0 = (j + 4 < jend) ? eid2[j + 4] : make_int2(0, -1);
        es1 = (j + 5 < jend) ? eid2[j + 5] : make_int2(0, -1);
        es2 = (j + 6 < jend) ? eid2[j + 6] : make_int2(0, -1);
        es3 = (j + 7 < jend) ? eid2[j + 7] : make_int2(0, -1);

        while (true) {
            // phase A: prefetch es -> B, load next indices, compute A
            LD_KV(kvB0, eaB0, es0) LD_KV(kvB1, eaB1, es1)
            LD_KV(kvB2, eaB2, es2) LD_KV(kvB3, eaB3, es3)
            es0 = (j + 8  < jend) ? eid2[j + 8]  : make_int2(0, -1);
            es1 = (j + 9  < jend) ? eid2[j + 9]  : make_int2(0, -1);
            es2 = (j + 10 < jend) ? eid2[j + 10] : make_int2(0, -1);
            es3 = (j + 11 < jend) ? eid2[j + 11] : make_int2(0, -1);
            COMPUTE(kvA0, kvA1, kvA2, kvA3, eaA0, eaA1, eaA2, eaA3)
            j += 4;
            if (j >= jend) break;

            // phase B: prefetch es -> A, load next indices, compute B
            LD_KV(kvA0, eaA0, es0) LD_KV(kvA1, eaA1, es1)
            LD_KV(kvA2, eaA2, es2) LD_KV(kvA3, eaA3, es3)
            es0 = (j + 8  < jend) ? eid2[j + 8]  : make_int2(0, -1);
            es1 = (j + 9  < jend) ? eid2[j + 9]  : make_int2(0, -1);
            es2 = (j + 10 < jend) ? eid2[j + 10] : make_int2(0, -1);
            es3 = (j + 11 < jend) ? eid2[j + 11] : make_int2(0, -1);
            COMPUTE(kvB0, kvB1, kvB2, kvB3, eaB0, eaB1, eaB2, eaB3)
            j += 4;
            if (j >= jend) break;
        }
    }
    #undef LD_KV
    #undef COMPUTE

    float r = 1.f / (l + 1e-16f);
    weab[(size_t)node * 64 + lane] = f2bf(wacc * r);
    float ax = acc.x * r, ay = acc.y * r, az = acc.z * r, aw = acc.w * r;
    float mx = 0.5f * (ax + __shfl_xor(ax, 32));
    float my = 0.5f * (ay + __shfl_xor(ay, 32));
    float mz = 0.5f * (az + __shfl_xor(az, 32));
    float mw = 0.5f * (aw + __shfl_xor(aw, 32));
    if (lane < 32)
        *(float4*)(agg + (size_t)node * 128 + hl * 4) = make_float4(mx, my, mz, mw);
}

// ---------------------------------------------------------------------------
extern "C" void kernel_launch(void* const* d_in, const int* in_sizes, int n_in,
                              void* d_out, int out_size, void* d_ws, size_t ws_size,
                              hipStream_t stream) {
    const float* x    = (const float*)d_in[0];
    const int*   ei   = (const int*)d_in[1];
    const float* ea   = (const float*)d_in[2];
    const float* Wq   = (const float*)d_in[3];
    const float* bq   = (const float*)d_in[4];
    const float* Wk   = (const float*)d_in[5];
    const float* bk   = (const float*)d_in[6];
    const float* Wv   = (const float*)d_in[7];
    const float* bv   = (const float*)d_in[8];
    const float* We   = (const float*)d_in[9];
    const float* Wsk  = (const float*)d_in[10];
    const float* bsk  = (const float*)d_in[11];
    const float* g1   = (const float*)d_in[12];
    const float* b1l  = (const float*)d_in[13];
    const float* W1   = (const float*)d_in[14];
    const float* b1f  = (const float*)d_in[15];
    const float* W2   = (const float*)d_in[16];
    const float* b2f  = (const float*)d_in[17];
    const float* g2   = (const float*)d_in[18];
    const float* b2l  = (const float*)d_in[19];
    float* out = (float*)d_out;

    const int N = in_sizes[0] / 128;
    const int E = in_sizes[2] / 32;
    const int* src = ei;
    const int* dst = ei + E;

    char* w = (char*)d_ws;
    unsigned short* O1   = (unsigned short*)w;  w += (size_t)N * 2048;  // [N,1024] bf16
    float* agg           = (float*)w;           w += (size_t)N * 512;   // [N,128] f32
    unsigned short* weab = (unsigned short*)w;  w += (size_t)N * 128;   // [N,64] bf16
    unsigned short* hb   = (unsigned short*)w;  w += (size_t)N * 256;   // [N,128] bf16
    unsigned short* Wcat = (unsigned short*)w;  w += 1024 * 128 * 2;
    float* bcat          = (float*)w;           w += 1024 * 4;
    unsigned short* W1h  = (unsigned short*)w;  w += 256 * 128 * 2;
    unsigned short* W2h  = (unsigned short*)w;  w += 128 * 256 * 2;
    unsigned short* Wec2 = (unsigned short*)w;  w += 128 * 64 * 2;
    int2* eid2           = (int2*)w;            w += (size_t)E * 8;
    int* deg  = (int*)w;            // [N] — zeroed by memset (with cnt)
    int* cnt  = deg + N;            // [N]
    int* tmp  = cnt + N;            // [N]
    int* bsum = tmp + N;            // <=1024

    // mid (bf16 [N,256] = N*512 B) aliases agg (free after econ+LN1)
    unsigned short* mid = (unsigned short*)agg;

    const int gy128 = (N + 127) / 128;
    const int nb = (N + 255) / 256;

    // ---- zero deg+cnt (memset node), prep weights + deg_count ----
    hipMemsetAsync(deg, 0, (size_t)2 * N * 4, stream);
    prep_all<<<(WPREP + E + 255) / 256, 256, 0, stream>>>(
        Wq, bq, Wk, bk, Wv, bv, We, Wsk, bsk, W1, W2,
        Wcat, bcat, W1h, W2h, Wec2, dst, deg, E);

    // ---- fused projection GEMM (x cast folded): O1 = bf16(x) @ Wcat^T + bcat
    gemm_fused<0,0,1,1><<<dim3(8, gy128), 256, 0, stream>>>(
        x, 128, Wcat, 128, bcat, O1, 1024, N, 128,
        nullptr, nullptr, nullptr, 0, nullptr, nullptr, nullptr);

    // ---- CSR: scan + fill (no rowp/finalize) ----
    scan_block<<<nb, 256, 0, stream>>>(deg, tmp, bsum, N);
    scan_bsum<<<1, 1024, 0, stream>>>(bsum, nb);
    csr_fill<<<(E + 255)/256, 256, 0, stream>>>(src, dst, tmp, bsum, cnt, eid2, E);

    // ---- attention (1 wave/node, 4-deep ping-pong) ----
    fused_attn<<<(N + 3) / 4, 256, 0, stream>>>(O1, ea, tmp, bsum, eid2, agg, weab, N);

    // ---- econ GEMM + LN1 fused: hb = LN1(weab@Wec2^T + agg + x + skip) ----
    gemm_fused<0,1,1,0><<<dim3(1, gy128), 256, 0, stream>>>(
        weab, 64, Wec2, 64, nullptr, hb, 128, N, 64,
        agg, x, O1 + 768, 1024, nullptr, g1, b1l);

    // ---- FFN1: mid = leaky(hb @ W1h^T + b1f) ----
    gemm_fused<1,0,1,0><<<dim3(2, gy128), 256, 0, stream>>>(
        hb, 128, W1h, 128, b1f, mid, 256, N, 128,
        nullptr, nullptr, nullptr, 0, nullptr, nullptr, nullptr);

    // ---- FFN2 + LN2 fused: out = LN2(hb + mid @ W2h^T + b2f) ----
    gemm_fused<0,2,0,0><<<dim3(1, gy128), 256, 0, stream>>>(
        mid, 256, W2h, 256, b2f, out, 128, N, 256,
        nullptr, nullptr, nullptr, 0, hb, g2, b2l);
}

// Round 9
// 397.596 us; speedup vs baseline: 1.0972x; 1.0972x over previous
//
#include <hip/hip_runtime.h>
#include <hip/hip_bf16.h>

// ---------------------------------------------------------------------------
// GraphTransformerBlock: TransformerConv(H=2, C=128) + skip + LN + FFN + LN
// R9: R8 with the ping-pong loop-guard bug fixed (while (j < jend), not
// while(true) — phase A must never run with j >= jend since its w0 is
// unguarded; R8 added a phantom exp(0) edge for deg%4 in {0,3}).
// fused_attn = 1 wave / 64-thread block, 2-edge ping-pong, head-mean epilogue.
// O1 row [1024]: q 0-255 | kv-interleaved 256-767 | skip 768-895 | P 896-959
// ---------------------------------------------------------------------------

typedef __attribute__((ext_vector_type(8))) short bf16x8;
typedef __attribute__((ext_vector_type(8))) unsigned short u16x8;
typedef __attribute__((ext_vector_type(4))) float f32x4;

__device__ __forceinline__ float bf2f(unsigned short u) {
    union { float f; unsigned u32; } x; x.u32 = ((unsigned)u) << 16; return x.f;
}
__device__ __forceinline__ unsigned short f2bf(float f) {
    unsigned u = __float_as_uint(f);
    return (unsigned short)((u + 0x7FFFu + ((u >> 16) & 1u)) >> 16);
}

// ---------------- bf16 MFMA GEMM + optional fused LN epilogue ---------------
// C[M,OC] = act(A[M,K] @ W[OC,K]^T + bias)
// AF32=1: A is fp32, converted to bf16 during LDS staging.
// EPI=0: plain store. EPI=1 (grid.x==1, OC=128): t = acc+add0+add1+bf16(skip);
// out = LN(t) -> bf16. EPI=2: f = acc+bias; t = bf16(hprev)+f; LN -> f32.
template<int ACT, int EPI, int OUT_BF16, int AF32>
__global__ __launch_bounds__(256)
void gemm_fused(const void* __restrict__ Ap, int lda,
                const unsigned short* __restrict__ W, int ldw,
                const float* __restrict__ bias,
                void* __restrict__ outp, int ldo, int M, int K,
                const float* __restrict__ add0, const float* __restrict__ add1,
                const unsigned short* __restrict__ skipp, int skip_ld,
                const unsigned short* __restrict__ hprev,
                const float* __restrict__ lng, const float* __restrict__ lnb) {
    __shared__ unsigned short As[128 * 40];   // pitch 40 elems kills conflicts
    __shared__ unsigned short Bs[128 * 40];
    const int tid = threadIdx.x;
    const int wave = tid >> 6, lane = tid & 63;
    const int row0 = blockIdx.y * 128, col0 = blockIdx.x * 128;
    const int srow = tid >> 2;
    const int skg  = (tid & 3) * 8;
    int r0 = row0 + srow;      if (r0 >= M) r0 = 0;
    int r1 = row0 + srow + 64; if (r1 >= M) r1 = 0;
    const int b0 = col0 + srow, b1 = col0 + srow + 64;

    f32x4 acc[2][8];
    const f32x4 z4 = {0.f, 0.f, 0.f, 0.f};
    #pragma unroll
    for (int i = 0; i < 2; i++)
        #pragma unroll
        for (int j = 0; j < 8; j++) acc[i][j] = z4;

    const int mrow = wave * 32 + (lane & 15);
    const int kq = (lane >> 4) * 8;

    for (int kt = 0; kt < K; kt += 32) {
        u16x8 a0v, a1v;
        if (AF32) {
            const float* Af = (const float*)Ap;
            float4 xa = *(const float4*)(Af + (size_t)r0 * lda + kt + skg);
            float4 xb = *(const float4*)(Af + (size_t)r0 * lda + kt + skg + 4);
            float4 ya = *(const float4*)(Af + (size_t)r1 * lda + kt + skg);
            float4 yb = *(const float4*)(Af + (size_t)r1 * lda + kt + skg + 4);
            a0v[0]=f2bf(xa.x); a0v[1]=f2bf(xa.y); a0v[2]=f2bf(xa.z); a0v[3]=f2bf(xa.w);
            a0v[4]=f2bf(xb.x); a0v[5]=f2bf(xb.y); a0v[6]=f2bf(xb.z); a0v[7]=f2bf(xb.w);
            a1v[0]=f2bf(ya.x); a1v[1]=f2bf(ya.y); a1v[2]=f2bf(ya.z); a1v[3]=f2bf(ya.w);
            a1v[4]=f2bf(yb.x); a1v[5]=f2bf(yb.y); a1v[6]=f2bf(yb.z); a1v[7]=f2bf(yb.w);
        } else {
            const unsigned short* Ah = (const unsigned short*)Ap;
            a0v = *(const u16x8*)(Ah + (size_t)r0 * lda + kt + skg);
            a1v = *(const u16x8*)(Ah + (size_t)r1 * lda + kt + skg);
        }
        float4 w0 = *(const float4*)(W + (size_t)b0 * ldw + kt + skg);
        float4 w1 = *(const float4*)(W + (size_t)b1 * ldw + kt + skg);
        __syncthreads();
        *(u16x8*)&As[srow * 40 + skg]        = a0v;
        *(u16x8*)&As[(srow + 64) * 40 + skg] = a1v;
        *(float4*)&Bs[srow * 40 + skg]        = w0;
        *(float4*)&Bs[(srow + 64) * 40 + skg] = w1;
        __syncthreads();
        bf16x8 af0 = *(const bf16x8*)&As[mrow * 40 + kq];
        bf16x8 af1 = *(const bf16x8*)&As[(mrow + 16) * 40 + kq];
        bf16x8 bfr[8];
        #pragma unroll
        for (int j = 0; j < 8; j++)
            bfr[j] = *(const bf16x8*)&Bs[(j * 16 + (lane & 15)) * 40 + kq];
        #pragma unroll
        for (int j = 0; j < 8; j++) {
            acc[0][j] = __builtin_amdgcn_mfma_f32_16x16x32_bf16(af0, bfr[j], acc[0][j], 0, 0, 0);
            acc[1][j] = __builtin_amdgcn_mfma_f32_16x16x32_bf16(af1, bfr[j], acc[1][j], 0, 0, 0);
        }
    }

    // C/D layout: col = lane&15, row = (lane>>4)*4 + reg
    const int lgrp = lane & 15;
    if (EPI == 0) {
        const int orow0 = row0 + wave * 32 + ((lane >> 4) << 2);
        const int ocol0 = col0 + lgrp;
        #pragma unroll
        for (int i = 0; i < 2; i++) {
            #pragma unroll
            for (int r = 0; r < 4; r++) {
                int row = orow0 + i * 16 + r;
                if (row >= M) continue;
                #pragma unroll
                for (int j = 0; j < 8; j++) {
                    int col = ocol0 + j * 16;
                    float v = acc[i][j][r] + (bias ? bias[col] : 0.f);
                    if (ACT == 1) v = (v > 0.f) ? v : 0.01f * v;
                    if (OUT_BF16) ((unsigned short*)outp)[(size_t)row * ldo + col] = f2bf(v);
                    else          ((float*)outp)[(size_t)row * ldo + col] = v;
                }
            }
        }
    } else {
        #pragma unroll
        for (int i = 0; i < 2; i++) {
            #pragma unroll
            for (int r = 0; r < 4; r++) {
                int row = row0 + wave * 32 + ((lane >> 4) << 2) + i * 16 + r;
                if (row >= M) continue;
                float t[8];
                #pragma unroll
                for (int j = 0; j < 8; j++) {
                    int col = lgrp + j * 16;
                    float v = acc[i][j][r];
                    if (EPI == 1) {
                        v += add0[(size_t)row * 128 + col] + add1[(size_t)row * 128 + col]
                           + bf2f(skipp[(size_t)row * skip_ld + col]);
                    } else {
                        v += bias[col];
                        v += bf2f(hprev[(size_t)row * 128 + col]);
                    }
                    t[j] = v;
                }
                float s = 0.f;
                #pragma unroll
                for (int j = 0; j < 8; j++) s += t[j];
                #pragma unroll
                for (int off = 8; off >= 1; off >>= 1) s += __shfl_xor(s, off);
                float mu = s * (1.f / 128.f);
                float q = 0.f;
                #pragma unroll
                for (int j = 0; j < 8; j++) { float d = t[j] - mu; q += d * d; }
                #pragma unroll
                for (int off = 8; off >= 1; off >>= 1) q += __shfl_xor(q, off);
                float rs = rsqrtf(q * (1.f / 128.f) + 1e-5f);
                #pragma unroll
                for (int j = 0; j < 8; j++) {
                    int col = lgrp + j * 16;
                    float o = (t[j] - mu) * rs * lng[col] + lnb[col];
                    if (EPI == 1) ((unsigned short*)outp)[(size_t)row * ldo + col] = f2bf(o);
                    else          ((float*)outp)[(size_t)row * ldo + col] = o;
                }
            }
        }
    }
}

// ---------------- prep: weights + deg_count, one dispatch -------------------
#define WPREP 205824
__global__ void prep_all(const float* __restrict__ Wq, const float* __restrict__ bq,
                         const float* __restrict__ Wk, const float* __restrict__ bk,
                         const float* __restrict__ Wv, const float* __restrict__ bv,
                         const float* __restrict__ We, const float* __restrict__ Wsk,
                         const float* __restrict__ bsk,
                         const float* __restrict__ W1, const float* __restrict__ W2,
                         unsigned short* __restrict__ Wcat, float* __restrict__ bcat,
                         unsigned short* __restrict__ W1h, unsigned short* __restrict__ W2h,
                         unsigned short* __restrict__ Wec2,
                         const int* __restrict__ dst, int* __restrict__ deg, int E) {
    int k = blockIdx.x * 256 + threadIdx.x;
    if (k >= WPREP) {                       // deg count segment
        int e = k - WPREP;
        if (e < E) atomicAdd(&deg[dst[e]], 1);
        return;
    }
    if (k < 131072) {                       // Wcat [1024][128]
        int oc = k >> 7, r = k & 127;
        float v;
        if (oc < 256) v = Wq[(size_t)oc * 128 + r];
        else if (oc < 768) {
            int rr = oc - 256, g = rr >> 3, p = rr & 7;
            int h = g >> 5, ch = h * 128 + (g & 31) * 4 + (p & 3);
            v = (p < 4) ? Wk[(size_t)ch * 128 + r] : Wv[(size_t)ch * 128 + r];
        } else if (oc < 896) v = Wsk[(size_t)(oc - 768) * 128 + r];
        else if (oc < 960) {
            int qd = oc - 896, h = qd >> 5, t = qd & 31;
            float s = 0.f;
            for (int c = 0; c < 128; c++)
                s += Wq[(size_t)(h*128 + c) * 128 + r] * We[(size_t)(h*128 + c) * 32 + t];
            v = s;
        } else v = 0.f;
        Wcat[k] = f2bf(v);
    } else if (k < 132096) {                // bcat [1024]
        int oc = k - 131072;
        float v;
        if (oc < 256) v = bq[oc];
        else if (oc < 768) {
            int rr = oc - 256, g = rr >> 3, p = rr & 7;
            int ch = (g >> 5) * 128 + (g & 31) * 4 + (p & 3);
            v = (p < 4) ? bk[ch] : bv[ch];
        } else if (oc < 896) v = bsk[oc - 768];
        else if (oc < 960) {
            int qd = oc - 896, h = qd >> 5, t = qd & 31;
            float s = 0.f;
            for (int c = 0; c < 128; c++)
                s += bq[h*128 + c] * We[(size_t)(h*128 + c) * 32 + t];
            v = s;
        } else v = 0.f;
        bcat[oc] = v;
    } else if (k < 164864) {                // W1h
        int j = k - 132096;
        W1h[j] = f2bf(W1[j]);
    } else if (k < 197632) {                // W2h
        int j = k - 164864;
        W2h[j] = f2bf(W2[j]);
    } else {                                // Wec2 [128][64], 0.5 head-mean folded
        int j = k - 197632;
        int c = j >> 6, tt = j & 63, h = tt >> 5, t = tt & 31;
        Wec2[j] = f2bf(0.5f * We[(size_t)(h * 128 + c) * 32 + t]);
    }
}

// ---------------- CSR scan --------------------------------------------------
__global__ __launch_bounds__(256)
void scan_block(const int* __restrict__ deg, int* __restrict__ tmp,
                int* __restrict__ bsum, int n) {
    __shared__ int lds[256];
    int i = blockIdx.x * 256 + threadIdx.x;
    int v = (i < n) ? deg[i] : 0;
    lds[threadIdx.x] = v;
    __syncthreads();
    #pragma unroll
    for (int off = 1; off < 256; off <<= 1) {
        int t = (threadIdx.x >= off) ? lds[threadIdx.x - off] : 0;
        __syncthreads();
        lds[threadIdx.x] += t;
        __syncthreads();
    }
    if (i < n) tmp[i] = lds[threadIdx.x];
    if (threadIdx.x == 255) bsum[blockIdx.x] = lds[255];
}
__global__ __launch_bounds__(1024)
void scan_bsum(int* __restrict__ bsum, int nb) {
    __shared__ int lds[1024];
    int v = (threadIdx.x < nb) ? bsum[threadIdx.x] : 0;
    lds[threadIdx.x] = v;
    __syncthreads();
    #pragma unroll
    for (int off = 1; off < 1024; off <<= 1) {
        int t = (threadIdx.x >= off) ? lds[threadIdx.x - off] : 0;
        __syncthreads();
        lds[threadIdx.x] += t;
        __syncthreads();
    }
    if (threadIdx.x < nb) bsum[threadIdx.x] = lds[threadIdx.x] - v;  // exclusive
}
// row_start(d) = (d==0) ? 0 : tmp[d-1] + sbx[(d-1)>>8]
__global__ void csr_fill(const int* __restrict__ src, const int* __restrict__ dst,
                         const int* __restrict__ tmp, const int* __restrict__ sbx,
                         int* __restrict__ cnt, int2* __restrict__ eid2, int E) {
    int e = blockIdx.x * blockDim.x + threadIdx.x;
    if (e < E) {
        int d = dst[e];
        int start = (d == 0) ? 0 : (tmp[d - 1] + sbx[(d - 1) >> 8]);
        int pos = start + atomicAdd(&cnt[d], 1);
        eid2[pos] = make_int2(e, src[e]);
    }
}

// ---------------- fused attention: 1 wave/block, 2-edge ping-pong -----------
// Loop invariant: phase A only entered with j < jend (w0 unguarded there).
// Epilogue: per-head normalize, head-mean via shfl_xor(32) -> agg[N,128].
__global__ __launch_bounds__(64)
void fused_attn(const unsigned short* __restrict__ O1, const float* __restrict__ EA,
                const int* __restrict__ tmp, const int* __restrict__ sbx,
                const int2* __restrict__ eid2,
                float* __restrict__ agg, unsigned short* __restrict__ weab, int N) {
    const int node = blockIdx.x;
    const int lane = threadIdx.x;
    const int hl = lane & 31;
    const int choff = (lane >> 5) * 128 + (hl << 2);
    const float inv = 0.08838834764831845f;  // 1/sqrt(128)

    ushort4 q4 = *(const ushort4*)(O1 + (size_t)node * 1024 + choff);
    float4 qv = make_float4(bf2f(q4.x), bf2f(q4.y), bf2f(q4.z), bf2f(q4.w));
    float pd = bf2f(O1[(size_t)node * 1024 + 896 + lane]);

    const int j0 = (node == 0) ? 0 : (tmp[node - 1] + sbx[(node - 1) >> 8]);
    const int jend = tmp[node] + sbx[node >> 8];

    float l = 0.f, wacc = 0.f;
    float4 acc = make_float4(0.f, 0.f, 0.f, 0.f);

    const u16x8 zkv = {0,0,0,0,0,0,0,0};
    u16x8 kvA0, kvA1, kvB0, kvB1;
    float eaA0, eaA1, eaB0, eaB1;
    int2 es0, es1;

    int j = j0;
    if (j < jend) {
        // chunk 0 data -> A
        {
            int2 es = eid2[j];
            kvA0 = *(const u16x8*)(O1 + (size_t)es.y * 1024 + 256 + lane * 8);
            eaA0 = EA[(size_t)es.x * 32 + hl];
        }
        if (j + 1 < jend) {
            int2 es = eid2[j + 1];
            kvA1 = *(const u16x8*)(O1 + (size_t)es.y * 1024 + 256 + lane * 8);
            eaA1 = EA[(size_t)es.x * 32 + hl];
        } else { kvA1 = zkv; eaA1 = 0.f; }
        // chunk 1 indices
        es0 = (j + 2 < jend) ? eid2[j + 2] : make_int2(0, -1);
        es1 = (j + 3 < jend) ? eid2[j + 3] : make_int2(0, -1);

        while (j < jend) {
            // phase A: prefetch next chunk -> B, next-next indices -> es, compute A
            if (es0.y >= 0) {
                kvB0 = *(const u16x8*)(O1 + (size_t)es0.y * 1024 + 256 + lane * 8);
                eaB0 = EA[(size_t)es0.x * 32 + hl];
            } else { kvB0 = zkv; eaB0 = 0.f; }
            if (es1.y >= 0) {
                kvB1 = *(const u16x8*)(O1 + (size_t)es1.y * 1024 + 256 + lane * 8);
                eaB1 = EA[(size_t)es1.x * 32 + hl];
            } else { kvB1 = zkv; eaB1 = 0.f; }
            es0 = (j + 4 < jend) ? eid2[j + 4] : make_int2(0, -1);
            es1 = (j + 5 < jend) ? eid2[j + 5] : make_int2(0, -1);
            {
                float d0 = qv.x*bf2f(kvA0[0]) + qv.y*bf2f(kvA0[1])
                         + qv.z*bf2f(kvA0[2]) + qv.w*bf2f(kvA0[3]) + pd*eaA0;
                float d1 = qv.x*bf2f(kvA1[0]) + qv.y*bf2f(kvA1[1])
                         + qv.z*bf2f(kvA1[2]) + qv.w*bf2f(kvA1[3]) + pd*eaA1;
                #pragma unroll
                for (int off = 16; off >= 1; off >>= 1) {
                    d0 += __shfl_xor(d0, off);
                    d1 += __shfl_xor(d1, off);
                }
                float w0 = __expf(d0 * inv);                       // j < jend by loop invariant
                float w1 = (j + 1 < jend) ? __expf(d1 * inv) : 0.f;
                l += w0 + w1;
                acc.x += w0*bf2f(kvA0[4]) + w1*bf2f(kvA1[4]);
                acc.y += w0*bf2f(kvA0[5]) + w1*bf2f(kvA1[5]);
                acc.z += w0*bf2f(kvA0[6]) + w1*bf2f(kvA1[6]);
                acc.w += w0*bf2f(kvA0[7]) + w1*bf2f(kvA1[7]);
                wacc  += w0*eaA0 + w1*eaA1;
            }
            j += 2;
            if (j >= jend) break;

            // phase B: prefetch -> A, compute B (j < jend guaranteed here)
            if (es0.y >= 0) {
                kvA0 = *(const u16x8*)(O1 + (size_t)es0.y * 1024 + 256 + lane * 8);
                eaA0 = EA[(size_t)es0.x * 32 + hl];
            } else { kvA0 = zkv; eaA0 = 0.f; }
            if (es1.y >= 0) {
                kvA1 = *(const u16x8*)(O1 + (size_t)es1.y * 1024 + 256 + lane * 8);
                eaA1 = EA[(size_t)es1.x * 32 + hl];
            } else { kvA1 = zkv; eaA1 = 0.f; }
            es0 = (j + 4 < jend) ? eid2[j + 4] : make_int2(0, -1);
            es1 = (j + 5 < jend) ? eid2[j + 5] : make_int2(0, -1);
            {
                float d0 = qv.x*bf2f(kvB0[0]) + qv.y*bf2f(kvB0[1])
                         + qv.z*bf2f(kvB0[2]) + qv.w*bf2f(kvB0[3]) + pd*eaB0;
                float d1 = qv.x*bf2f(kvB1[0]) + qv.y*bf2f(kvB1[1])
                         + qv.z*bf2f(kvB1[2]) + qv.w*bf2f(kvB1[3]) + pd*eaB1;
                #pragma unroll
                for (int off = 16; off >= 1; off >>= 1) {
                    d0 += __shfl_xor(d0, off);
                    d1 += __shfl_xor(d1, off);
                }
                float w0 = __expf(d0 * inv);
                float w1 = (j + 1 < jend) ? __expf(d1 * inv) : 0.f;
                l += w0 + w1;
                acc.x += w0*bf2f(kvB0[4]) + w1*bf2f(kvB1[4]);
                acc.y += w0*bf2f(kvB0[5]) + w1*bf2f(kvB1[5]);
                acc.z += w0*bf2f(kvB0[6]) + w1*bf2f(kvB1[6]);
                acc.w += w0*bf2f(kvB0[7]) + w1*bf2f(kvB1[7]);
                wacc  += w0*eaB0 + w1*eaB1;
            }
            j += 2;
        }
    }

    float r = 1.f / (l + 1e-16f);
    weab[(size_t)node * 64 + lane] = f2bf(wacc * r);
    float ax = acc.x * r, ay = acc.y * r, az = acc.z * r, aw = acc.w * r;
    float mx = 0.5f * (ax + __shfl_xor(ax, 32));
    float my = 0.5f * (ay + __shfl_xor(ay, 32));
    float mz = 0.5f * (az + __shfl_xor(az, 32));
    float mw = 0.5f * (aw + __shfl_xor(aw, 32));
    if (lane < 32)
        *(float4*)(agg + (size_t)node * 128 + hl * 4) = make_float4(mx, my, mz, mw);
}

// ---------------------------------------------------------------------------
extern "C" void kernel_launch(void* const* d_in, const int* in_sizes, int n_in,
                              void* d_out, int out_size, void* d_ws, size_t ws_size,
                              hipStream_t stream) {
    const float* x    = (const float*)d_in[0];
    const int*   ei   = (const int*)d_in[1];
    const float* ea   = (const float*)d_in[2];
    const float* Wq   = (const float*)d_in[3];
    const float* bq   = (const float*)d_in[4];
    const float* Wk   = (const float*)d_in[5];
    const float* bk   = (const float*)d_in[6];
    const float* Wv   = (const float*)d_in[7];
    const float* bv   = (const float*)d_in[8];
    const float* We   = (const float*)d_in[9];
    const float* Wsk  = (const float*)d_in[10];
    const float* bsk  = (const float*)d_in[11];
    const float* g1   = (const float*)d_in[12];
    const float* b1l  = (const float*)d_in[13];
    const float* W1   = (const float*)d_in[14];
    const float* b1f  = (const float*)d_in[15];
    const float* W2   = (const float*)d_in[16];
    const float* b2f  = (const float*)d_in[17];
    const float* g2   = (const float*)d_in[18];
    const float* b2l  = (const float*)d_in[19];
    float* out = (float*)d_out;

    const int N = in_sizes[0] / 128;
    const int E = in_sizes[2] / 32;
    const int* src = ei;
    const int* dst = ei + E;

    char* w = (char*)d_ws;
    unsigned short* O1   = (unsigned short*)w;  w += (size_t)N * 2048;  // [N,1024] bf16
    float* agg           = (float*)w;           w += (size_t)N * 512;   // [N,128] f32
    unsigned short* weab = (unsigned short*)w;  w += (size_t)N * 128;   // [N,64] bf16
    unsigned short* hb   = (unsigned short*)w;  w += (size_t)N * 256;   // [N,128] bf16
    unsigned short* Wcat = (unsigned short*)w;  w += 1024 * 128 * 2;
    float* bcat          = (float*)w;           w += 1024 * 4;
    unsigned short* W1h  = (unsigned short*)w;  w += 256 * 128 * 2;
    unsigned short* W2h  = (unsigned short*)w;  w += 128 * 256 * 2;
    unsigned short* Wec2 = (unsigned short*)w;  w += 128 * 64 * 2;
    int2* eid2           = (int2*)w;            w += (size_t)E * 8;
    int* deg  = (int*)w;            // [N] — zeroed by memset (with cnt)
    int* cnt  = deg + N;            // [N]
    int* tmp  = cnt + N;            // [N]
    int* bsum = tmp + N;            // <=1024

    // mid (bf16 [N,256] = N*512 B) aliases agg (free after econ+LN1)
    unsigned short* mid = (unsigned short*)agg;

    const int gy128 = (N + 127) / 128;
    const int nb = (N + 255) / 256;

    // ---- zero deg+cnt (memset node), prep weights + deg_count ----
    hipMemsetAsync(deg, 0, (size_t)2 * N * 4, stream);
    prep_all<<<(WPREP + E + 255) / 256, 256, 0, stream>>>(
        Wq, bq, Wk, bk, Wv, bv, We, Wsk, bsk, W1, W2,
        Wcat, bcat, W1h, W2h, Wec2, dst, deg, E);

    // ---- fused projection GEMM (x cast folded): O1 = bf16(x) @ Wcat^T + bcat
    gemm_fused<0,0,1,1><<<dim3(8, gy128), 256, 0, stream>>>(
        x, 128, Wcat, 128, bcat, O1, 1024, N, 128,
        nullptr, nullptr, nullptr, 0, nullptr, nullptr, nullptr);

    // ---- CSR: scan + fill ----
    scan_block<<<nb, 256, 0, stream>>>(deg, tmp, bsum, N);
    scan_bsum<<<1, 1024, 0, stream>>>(bsum, nb);
    csr_fill<<<(E + 255)/256, 256, 0, stream>>>(src, dst, tmp, bsum, cnt, eid2, E);

    // ---- attention (1 wave/block, 2-deep ping-pong) ----
    fused_attn<<<N, 64, 0, stream>>>(O1, ea, tmp, bsum, eid2, agg, weab, N);

    // ---- econ GEMM + LN1 fused: hb = LN1(weab@Wec2^T + agg + x + skip) ----
    gemm_fused<0,1,1,0><<<dim3(1, gy128), 256, 0, stream>>>(
        weab, 64, Wec2, 64, nullptr, hb, 128, N, 64,
        agg, x, O1 + 768, 1024, nullptr, g1, b1l);

    // ---- FFN1: mid = leaky(hb @ W1h^T + b1f) ----
    gemm_fused<1,0,1,0><<<dim3(2, gy128), 256, 0, stream>>>(
        hb, 128, W1h, 128, b1f, mid, 256, N, 128,
        nullptr, nullptr, nullptr, 0, nullptr, nullptr, nullptr);

    // ---- FFN2 + LN2 fused: out = LN2(hb + mid @ W2h^T + b2f) ----
    gemm_fused<0,2,0,0><<<dim3(1, gy128), 256, 0, stream>>>(
        mid, 256, W2h, 256, b2f, out, 128, N, 256,
        nullptr, nullptr, nullptr, 0, hb, g2, b2l);
}